// Round 4
// baseline (330.793 us; speedup 1.0000x reference)
//
#include <hip/hip_runtime.h>
#include <cstdint>
#include <cstddef>

typedef unsigned short u16;
typedef __attribute__((ext_vector_type(8))) short short8v;   // 8 x bf16 (4 VGPRs)
typedef __attribute__((ext_vector_type(4))) float f32x4;

#define B_   2
#define L_   2048
#define D_   1024
#define NH_  16
#define DH_  64
#define M_   (B_*L_)      /* 4096 */
#define N4_  (4*D_)       /* 4096 */

__device__ __forceinline__ float bf2f(u16 u) {
  union { float f; unsigned int i; } v; v.i = ((unsigned int)u) << 16; return v.f;
}
__device__ __forceinline__ u16 f2bf(float f) {
  union { float f; unsigned int i; } v; v.f = f;
  unsigned int x = v.i;
  return (u16)((x + 0x7fffu + ((x >> 16) & 1u)) >> 16);   // RNE
}
__device__ __forceinline__ unsigned int pk_bf16(float a, float b) {
#if __has_builtin(__builtin_amdgcn_cvt_pk_bf16_f32)
  auto r = __builtin_amdgcn_cvt_pk_bf16_f32(a, b);
  union { decltype(r) v; unsigned int u; } c; c.v = r; return c.u;
#else
  return (unsigned int)f2bf(a) | ((unsigned int)f2bf(b) << 16);
#endif
}
__device__ __forceinline__ float siluf(float x) { return x / (1.0f + __expf(-x)); }

// async global->LDS, 16B per lane. LDS dest = wave-uniform base + lane*16.
__device__ __forceinline__ void gl2lds16(const u16* g, u16* l) {
  __builtin_amdgcn_global_load_lds(
      (const __attribute__((address_space(1))) unsigned int*)(const void*)g,
      (__attribute__((address_space(3))) unsigned int*)(void*)l,
      16, 0, 0);
}

// ---------------------------------------------------------------- convert + cumsum (fused)
__global__ __launch_bounds__(256) void k_conv_cum(const float* __restrict__ x,
                                                  const float* __restrict__ pw,
                                                  const float* __restrict__ ow,
                                                  const float* __restrict__ lam,
                                                  u16* __restrict__ xb,
                                                  u16* __restrict__ pwb,
                                                  u16* __restrict__ owb,
                                                  float* __restrict__ pos) {
  const int NX = M_ * D_ / 4, NP = N4_ * D_ / 4;
  int bid = blockIdx.x;
  int tid = threadIdx.x;
  if (bid < 9216) {
    int i = bid * 256 + tid;
    const float* src; u16* dst; int j;
    if (i < NX)            { src = x;  dst = xb;  j = i; }
    else if (i < NX + NP)  { src = pw; dst = pwb; j = i - NX; }
    else                   { src = ow; dst = owb; j = i - NX - NP; }
    float4 v = ((const float4*)src)[j];
    ushort4 o; o.x = f2bf(v.x); o.y = f2bf(v.y); o.z = f2bf(v.z); o.w = f2bf(v.w);
    ((ushort4*)dst)[j] = o;
  } else {
    int b = bid - 9216;
    const float* in = lam + (size_t)b * L_;
    float* out = pos + (size_t)b * L_;
    float loc[8], s = 0.0f;
#pragma unroll
    for (int i = 0; i < 8; ++i) { loc[i] = in[tid * 8 + i]; s += loc[i]; }
    __shared__ float sb[256];
    sb[tid] = s;
    __syncthreads();
    for (int off = 1; off < 256; off <<= 1) {
      float t = (tid >= off) ? sb[tid - off] : 0.0f;
      __syncthreads();
      sb[tid] += t;
      __syncthreads();
    }
    float run = sb[tid] - s;   // exclusive prefix
#pragma unroll
    for (int i = 0; i < 8; ++i) { run += loc[i]; out[tid * 8 + i] = run; }
  }
}

// ---------------------------------------------------------------- GEMM1: h = silu(x @ pw^T + pb), split u/v/q/k
// double-buffered single-barrier K-loop; swizzled LDS (conflict-free frag reads)
__global__ __launch_bounds__(256, 4) void k_gemm1(const u16* __restrict__ A,
                                                  const u16* __restrict__ Bw,
                                                  const float* __restrict__ bias,
                                                  u16* __restrict__ hu, u16* __restrict__ hv,
                                                  u16* __restrict__ hq, u16* __restrict__ hk) {
  const int K = D_;
  int bn = blockIdx.x, bm = blockIdx.y, tid = threadIdx.x;
  int w = tid >> 6, lane = tid & 63, quad = lane >> 4, r16 = lane & 15;
  __shared__ __align__(16) u16 As[8192], Bs[8192];   // 2 buffers x 128x32
  const u16* gA = A  + (size_t)(bm * 128) * K;
  const u16* gB = Bw + (size_t)(bn * 128) * K;
  int srow = tid >> 2, sc = tid & 3;
  // prologue stage(0)
#pragma unroll
  for (int s = 0; s < 2; ++s) {
    int row = s * 64 + srow;
    int q = (sc - (row >> 1)) & 3;
    gl2lds16(gA + (size_t)row * K + q * 8, As + s * 2048 + w * 512);
    gl2lds16(gB + (size_t)row * K + q * 8, Bs + s * 2048 + w * 512);
  }
  f32x4 acc[4][4] = {};
  int wm = w & 1, wn = w >> 1;
  const int rowb = wm * 64, colb = wn * 64;
  for (int n = 0; n < 32; ++n) {
    __syncthreads();                       // drains stage(n)
    if (n + 1 < 32) {
      int kt = (n + 1) * 32, pb = (n + 1) & 1;
#pragma unroll
      for (int s = 0; s < 2; ++s) {
        int row = s * 64 + srow;
        int q = (sc - (row >> 1)) & 3;
        gl2lds16(gA + (size_t)row * K + kt + q * 8, As + pb * 4096 + s * 2048 + w * 512);
        gl2lds16(gB + (size_t)row * K + kt + q * 8, Bs + pb * 4096 + s * 2048 + w * 512);
      }
    }
    const u16* Ab = As + (n & 1) * 4096;
    const u16* Bb = Bs + (n & 1) * 4096;
    short8v af[4], bf[4];
#pragma unroll
    for (int mi = 0; mi < 4; ++mi) {
      int row = rowb + mi * 16 + r16;
      af[mi] = *(const short8v*)(Ab + (row * 4 + ((quad + (row >> 1)) & 3)) * 8);
    }
#pragma unroll
    for (int ni = 0; ni < 4; ++ni) {
      int row = colb + ni * 16 + r16;
      bf[ni] = *(const short8v*)(Bb + (row * 4 + ((quad + (row >> 1)) & 3)) * 8);
    }
#pragma unroll
    for (int mi = 0; mi < 4; ++mi)
#pragma unroll
      for (int ni = 0; ni < 4; ++ni)
        acc[mi][ni] = __builtin_amdgcn_mfma_f32_16x16x32_bf16(af[mi], bf[ni], acc[mi][ni], 0, 0, 0);
  }
  int nb = (bn * 128) >> 10;                 // which of u/v/q/k
  u16* dst = (nb == 0) ? hu : (nb == 1) ? hv : (nb == 2) ? hq : hk;
  int cbase = (bn * 128) & 1023;
  int row0 = bm * 128 + rowb;
#pragma unroll
  for (int ni = 0; ni < 4; ++ni) {
    int gcol = bn * 128 + colb + ni * 16 + r16;
    int lcol = cbase + colb + ni * 16 + r16;
    float bb = bias[gcol];
#pragma unroll
    for (int mi = 0; mi < 4; ++mi)
#pragma unroll
      for (int r = 0; r < 4; ++r) {
        int row = row0 + mi * 16 + quad * 4 + r;
        dst[(size_t)row * D_ + lcol] = f2bf(siluf(acc[mi][ni][r] + bb));
      }
  }
}

// ---------------------------------------------------------------- RoPE + gates (+head_scale into Q) and V gate+transpose (fused)
__global__ __launch_bounds__(256) void k_rope_vt(const u16* __restrict__ hq, const u16* __restrict__ hk,
                                                 const u16* __restrict__ hv,
                                                 const float* __restrict__ pos,
                                                 const float* __restrict__ qg, const float* __restrict__ kg,
                                                 const float* __restrict__ vg,
                                                 const float* __restrict__ hsc,
                                                 u16* __restrict__ Qb, u16* __restrict__ Kb,
                                                 u16* __restrict__ Vtb) {
  int bid = blockIdx.x;
  int tid = threadIdx.x;
  if (bid < 2048) {
    int idx = bid * 256 + tid;   // (bh*2048 + l)*8 + j4
    int j4 = idx & 7;
    int l  = (idx >> 3) & 2047;
    int bh = idx >> 14;
    int b = bh >> 4, hh = bh & 15;
    int row = b * L_ + l;
    float p = pos[row];
    float qs = qg[(size_t)row * NH_ + hh] * hsc[hh];
    float kgv = kg[(size_t)row * NH_ + hh];
    const u16* hqr = hq + (size_t)row * D_ + hh * DH_ + j4 * 8;
    const u16* hkr = hk + (size_t)row * D_ + hh * DH_ + j4 * 8;
    short8v qv = *(const short8v*)hqr;
    short8v kv = *(const short8v*)hkr;
    size_t ob = ((size_t)bh * L_ + l) * DH_ + j4 * 4;
    u16 qeo[4], qoo[4], keo[4], koo[4];
#pragma unroll
    for (int t = 0; t < 4; ++t) {
      int j = j4 * 4 + t;
      float inv = __expf(-(float)j * 0.28782313662425574f);  // 10000^(-2j/64)
      float a = p * inv;
      float c, s;
      __sincosf(a, &s, &c);
      float qe = bf2f((u16)qv[2 * t]), qo = bf2f((u16)qv[2 * t + 1]);
      float ke = bf2f((u16)kv[2 * t]), ko = bf2f((u16)kv[2 * t + 1]);
      qeo[t] = f2bf((qe * c - qo * s) * qs);
      qoo[t] = f2bf((qe * s + qo * c) * qs);
      keo[t] = f2bf((ke * c - ko * s) * kgv);
      koo[t] = f2bf((ke * s + ko * c) * kgv);
    }
    *(ushort4*)(Qb + ob)      = make_ushort4(qeo[0], qeo[1], qeo[2], qeo[3]);
    *(ushort4*)(Qb + ob + 32) = make_ushort4(qoo[0], qoo[1], qoo[2], qoo[3]);
    *(ushort4*)(Kb + ob)      = make_ushort4(keo[0], keo[1], keo[2], keo[3]);
    *(ushort4*)(Kb + ob + 32) = make_ushort4(koo[0], koo[1], koo[2], koo[3]);
  } else {
    int b2 = bid - 2048;
    int lt = b2 & 31;           // l-tile
    int bh = b2 >> 5;
    int b = bh >> 4, hh = bh & 15;
    __shared__ u16 t[64][68];   // pad to break transpose conflicts
    {
      int r = tid >> 2, cg = tid & 3;
      int row = b * L_ + lt * 64 + r;
      float gv = vg[(size_t)row * NH_ + hh];
      const u16* src = hv + (size_t)row * D_ + hh * DH_ + cg * 16;
      short8v v0 = ((const short8v*)src)[0];
      short8v v1 = ((const short8v*)src)[1];
#pragma unroll
      for (int e = 0; e < 8; ++e) {
        t[r][cg * 16 + e]     = f2bf(bf2f((u16)v0[e]) * gv);
        t[r][cg * 16 + 8 + e] = f2bf(bf2f((u16)v1[e]) * gv);
      }
    }
    __syncthreads();
    {
      int d = tid >> 2, lg = tid & 3;
      short8v o0, o1;
#pragma unroll
      for (int e = 0; e < 8; ++e) o0[e] = (short)t[lg * 16 + e][d];
#pragma unroll
      for (int e = 0; e < 8; ++e) o1[e] = (short)t[lg * 16 + 8 + e][d];
      u16* dst = Vtb + ((size_t)bh * DH_ + d) * L_ + lt * 64 + lg * 16;
      ((short8v*)dst)[0] = o0;
      ((short8v*)dst)[1] = o1;
    }
  }
}

// ---------------------------------------------------------------- fused causal gated attention + u-multiply
// v4: S^T QK (bias in acc-init, float4 bias loads, b64 Ps writes), swizzled conflict-free LDS,
//     PV A-prep = pure ds_read, Q in regs, 49 KB LDS -> 3 blocks/CU
__global__ __launch_bounds__(256, 3) void k_attn(const u16* __restrict__ Qb, const u16* __restrict__ Kb,
                                                 const u16* __restrict__ Vtb, const float* __restrict__ tpb,
                                                 const u16* __restrict__ hu, u16* __restrict__ A2) {
  int id = blockIdx.x;
  int group = id >> 5, bh = id & 31;
  int i64 = (group & 1) ? (group >> 1) : (31 - (group >> 1));
  int jmax = i64 >> 1;
  int b = bh >> 4, hh = bh & 15;
  int tid = threadIdx.x, w = tid >> 6, lane = tid & 63, quad = lane >> 4, r16 = lane & 15;
  int wj = w & 1, wi = w >> 1;
  __shared__ __align__(16) u16 Ks[8192];   // 2 k-slices x (128 j x 32 d), content-swizzled
  __shared__ __align__(16) u16 Vs[8192];   // 4 l-slices x (64 d x 32 l), content-swizzled
  __shared__ __align__(16) u16 Ps[8704];   // 64 i x 128 j bf16 P, row stride 136
  const size_t bhbase = (size_t)bh * L_ * DH_;
  int gibase = i64 * 64 + wi * 32;
  // Q fragments (B-operand: n=i, k=d)
  const u16* qt = Qb + bhbase + (size_t)gibase * DH_;
  short8v bq[2][2];
#pragma unroll
  for (int ks = 0; ks < 2; ++ks)
#pragma unroll
    for (int ti = 0; ti < 2; ++ti)
      bq[ks][ti] = *(const short8v*)(qt + (size_t)(ti * 16 + r16) * DH_ + ks * 32 + quad * 8);
  // stage K(0)
#pragma unroll
  for (int s = 0; s < 4; ++s) {
    int row = (s & 1) * 64 + (tid >> 2);
    int q = ((tid & 3) - (row >> 1)) & 3;
    gl2lds16(Kb + bhbase + (size_t)row * DH_ + (s >> 1) * 32 + q * 8, Ks + s * 2048 + w * 512);
  }
  f32x4 accy[4] = {};
  int gimax_w = i64 * 64 + w * 16 + 15;
  for (int jt = 0; jt <= jmax; ++jt) {
    __syncthreads();   // b1: K(jt) drained (covered by prior PV); Vs/Ps free
    // stage V(jt)
#pragma unroll
    for (int s = 0; s < 4; ++s) {
      int row = tid >> 2;
      int q = ((tid & 3) - (row >> 1)) & 3;
      gl2lds16(Vtb + bhbase + (size_t)row * L_ + jt * 128 + s * 32 + q * 8, Vs + s * 2048 + w * 512);
    }
    // ---- S^T = K·Q^T with acc preloaded with 4*bias; silu+mask+pack in epilogue
#pragma unroll
    for (int tj = 0; tj < 4; ++tj) {
      int jlo = jt * 128 + wj * 64 + tj * 16;     // global j base of tile
      bool anyM = jlo <= gibase + 31;
      short8v ak0, ak1;
      if (anyM) {
        int row = wj * 64 + tj * 16 + r16;
        int sw = (quad + (row >> 1)) & 3;
        ak0 = *(const short8v*)(Ks + (row * 4 + sw) * 8);
        ak1 = *(const short8v*)(Ks + 4096 + (row * 4 + sw) * 8);
      }
#pragma unroll
      for (int ti = 0; ti < 2; ++ti) {
        int gmaxt = gibase + ti * 16 + 15;
        bool doM = jlo <= gmaxt;              // tile has any unmasked element
        bool doW = (jlo & ~31) <= gmaxt;      // tile's k-slice is read by PV
        if (!doW) continue;
        unsigned int p01 = 0, p23 = 0;
        if (doM) {
          int gi = gibase + ti * 16 + r16;
          float4 bv = *(const float4*)(tpb + ((size_t)b * L_ + gi) * L_ + jlo + quad * 4);
          f32x4 acc;
          acc[0] = 4.0f * bv.x; acc[1] = 4.0f * bv.y; acc[2] = 4.0f * bv.z; acc[3] = 4.0f * bv.w;
          acc = __builtin_amdgcn_mfma_f32_16x16x32_bf16(ak0, bq[0][ti], acc, 0, 0, 0);
          acc = __builtin_amdgcn_mfma_f32_16x16x32_bf16(ak1, bq[1][ti], acc, 0, 0, 0);
          int j0 = jlo + quad * 4;
          float v0 = (j0     <= gi) ? siluf(acc[0]) : 0.0f;
          float v1 = (j0 + 1 <= gi) ? siluf(acc[1]) : 0.0f;
          float v2 = (j0 + 2 <= gi) ? siluf(acc[2]) : 0.0f;
          float v3 = (j0 + 3 <= gi) ? siluf(acc[3]) : 0.0f;
          p01 = pk_bf16(v0, v1);
          p23 = pk_bf16(v2, v3);
        }
        int iloc = wi * 32 + ti * 16 + r16;
        int jloc = wj * 64 + tj * 16 + quad * 4;
        *(uint2*)(Ps + iloc * 136 + jloc) = make_uint2(p01, p23);   // ds_write_b64
      }
    }
    __syncthreads();   // b2: Ps ready; V(jt) drained (covered by QK)
    // stage K(jt+1) (drains at next b1, covered by PV)
    if (jt < jmax) {
      const size_t kb = bhbase + (size_t)(jt + 1) * 128 * DH_;
#pragma unroll
      for (int s = 0; s < 4; ++s) {
        int row = (s & 1) * 64 + (tid >> 2);
        int q = ((tid & 3) - (row >> 1)) & 3;
        gl2lds16(Kb + kb + (size_t)row * DH_ + (s >> 1) * 32 + q * 8, Ks + s * 2048 + w * 512);
      }
    }
    // ---- PV: pure reads + mfma (wave w: rows w*16..w*16+15)
#pragma unroll
    for (int ks = 0; ks < 4; ++ks) {
      if (jt * 128 + ks * 32 > gimax_w) continue;
      short8v pa = *(const short8v*)(Ps + (w * 16 + r16) * 136 + ks * 32 + quad * 8);
#pragma unroll
      for (int ni = 0; ni < 4; ++ni) {
        int row = ni * 16 + r16;
        short8v vb = *(const short8v*)(Vs + ks * 2048 + (row * 4 + ((quad + (row >> 1)) & 3)) * 8);
        accy[ni] = __builtin_amdgcn_mfma_f32_16x16x32_bf16(pa, vb, accy[ni], 0, 0, 0);
      }
    }
  }
  // final epilogue: y * u -> A2 (b, l, h*64+d) bf16
#pragma unroll
  for (int ni = 0; ni < 4; ++ni) {
    int d = ni * 16 + r16;
#pragma unroll
    for (int r = 0; r < 4; ++r) {
      int lr = w * 16 + quad * 4 + r;
      size_t rowg = (size_t)b * L_ + (size_t)i64 * 64 + lr;
      float u = bf2f(hu[rowg * D_ + hh * DH_ + d]);
      A2[rowg * D_ + hh * DH_ + d] = f2bf(accy[ni][r] * u);
    }
  }
}

// ---------------------------------------------------------------- GEMM2: r = (y*u) @ ow^T + ob + x
__global__ __launch_bounds__(256, 4) void k_gemm2(const u16* __restrict__ A,
                                                  const u16* __restrict__ Bw,
                                                  const float* __restrict__ bias,
                                                  const float* __restrict__ xres,
                                                  float* __restrict__ out) {
  const int K = D_;
  int bn = blockIdx.x, bm = blockIdx.y, tid = threadIdx.x;
  int w = tid >> 6, lane = tid & 63, quad = lane >> 4, r16 = lane & 15;
  __shared__ __align__(16) u16 As[8192], Bs[8192];
  const u16* gA = A  + (size_t)(bm * 128) * K;
  const u16* gB = Bw + (size_t)(bn * 128) * K;
  int srow = tid >> 2, sc = tid & 3;
#pragma unroll
  for (int s = 0; s < 2; ++s) {
    int row = s * 64 + srow;
    int q = (sc - (row >> 1)) & 3;
    gl2lds16(gA + (size_t)row * K + q * 8, As + s * 2048 + w * 512);
    gl2lds16(gB + (size_t)row * K + q * 8, Bs + s * 2048 + w * 512);
  }
  f32x4 acc[4][4] = {};
  int wm = w & 1, wn = w >> 1;
  const int rowb = wm * 64, colb = wn * 64;
  for (int n = 0; n < 32; ++n) {
    __syncthreads();
    if (n + 1 < 32) {
      int kt = (n + 1) * 32, pb = (n + 1) & 1;
#pragma unroll
      for (int s = 0; s < 2; ++s) {
        int row = s * 64 + srow;
        int q = (sc - (row >> 1)) & 3;
        gl2lds16(gA + (size_t)row * K + kt + q * 8, As + pb * 4096 + s * 2048 + w * 512);
        gl2lds16(gB + (size_t)row * K + kt + q * 8, Bs + pb * 4096 + s * 2048 + w * 512);
      }
    }
    const u16* Ab = As + (n & 1) * 4096;
    const u16* Bb = Bs + (n & 1) * 4096;
    short8v af[4], bf[4];
#pragma unroll
    for (int mi = 0; mi < 4; ++mi) {
      int row = rowb + mi * 16 + r16;
      af[mi] = *(const short8v*)(Ab + (row * 4 + ((quad + (row >> 1)) & 3)) * 8);
    }
#pragma unroll
    for (int ni = 0; ni < 4; ++ni) {
      int row = colb + ni * 16 + r16;
      bf[ni] = *(const short8v*)(Bb + (row * 4 + ((quad + (row >> 1)) & 3)) * 8);
    }
#pragma unroll
    for (int mi = 0; mi < 4; ++mi)
#pragma unroll
      for (int ni = 0; ni < 4; ++ni)
        acc[mi][ni] = __builtin_amdgcn_mfma_f32_16x16x32_bf16(af[mi], bf[ni], acc[mi][ni], 0, 0, 0);
  }
  int row0 = bm * 128 + rowb, col0 = bn * 128 + colb;
#pragma unroll
  for (int ni = 0; ni < 4; ++ni) {
    int col = col0 + ni * 16 + r16;
    float bb = bias[col];
#pragma unroll
    for (int mi = 0; mi < 4; ++mi)
#pragma unroll
      for (int r = 0; r < 4; ++r) {
        int row = row0 + mi * 16 + quad * 4 + r;
        out[(size_t)row * D_ + col] = acc[mi][ni][r] + bb + xres[(size_t)row * D_ + col];
      }
  }
}

// ---------------------------------------------------------------- LayerNorm (in place on d_out)
__global__ __launch_bounds__(256) void k_ln(float* __restrict__ r,
                                            const float* __restrict__ g,
                                            const float* __restrict__ be) {
  int row = blockIdx.x, tid = threadIdx.x;
  float* pr = r + (size_t)row * D_;
  __shared__ float s1[4], s2[4];
  float v[4];
#pragma unroll
  for (int i = 0; i < 4; ++i) v[i] = pr[i * 256 + tid];
  float s = v[0] + v[1] + v[2] + v[3];
#pragma unroll
  for (int o = 32; o > 0; o >>= 1) s += __shfl_down(s, o, 64);
  if ((tid & 63) == 0) s1[tid >> 6] = s;
  __syncthreads();
  float mu = (s1[0] + s1[1] + s1[2] + s1[3]) * (1.0f / D_);
  float d = 0.0f;
#pragma unroll
  for (int i = 0; i < 4; ++i) { float t = v[i] - mu; d += t * t; }
#pragma unroll
  for (int o = 32; o > 0; o >>= 1) d += __shfl_down(d, o, 64);
  if ((tid & 63) == 0) s2[tid >> 6] = d;
  __syncthreads();
  float var = (s2[0] + s2[1] + s2[2] + s2[3]) * (1.0f / D_);
  float inv = rsqrtf(var + 1e-5f);
#pragma unroll
  for (int i = 0; i < 4; ++i) {
    int c = i * 256 + tid;
    pr[c] = (v[i] - mu) * inv * g[c] + be[c];
  }
}

// ---------------------------------------------------------------- launch
extern "C" void kernel_launch(void* const* d_in, const int* in_sizes, int n_in,
                              void* d_out, int out_size, void* d_ws, size_t ws_size,
                              hipStream_t stream) {
  const float* x   = (const float*)d_in[0];
  // d_in[1] attn_mask: deterministic causal tril -> not read
  // d_in[2] ts: unused by reference
  const float* lam = (const float*)d_in[3];
  const float* qg  = (const float*)d_in[4];
  const float* kg  = (const float*)d_in[5];
  const float* vg  = (const float*)d_in[6];
  const float* tpb = (const float*)d_in[7];
  const float* pw  = (const float*)d_in[8];
  const float* pb  = (const float*)d_in[9];
  const float* ow  = (const float*)d_in[10];
  const float* ob  = (const float*)d_in[11];
  const float* hsc = (const float*)d_in[12];
  const float* lng = (const float*)d_in[13];
  const float* lnb = (const float*)d_in[14];
  float* out = (float*)d_out;

  char* ws = (char*)d_ws;
  // layout (bytes). aliasing: Qb<-xb, Kb<-pwb, Vtb<-hq, A2<-hk (all after last read)
  u16* xb   = (u16*)(ws + 0);          // 8 MB   x bf16
  u16* pwb  = (u16*)(ws + 8388608);    // 8 MB   proj_w bf16
  u16* owb  = (u16*)(ws + 16777216);   // 2 MB   out_w bf16
  u16* hu   = (u16*)(ws + 18874368);   // 8 MB
  u16* hv   = (u16*)(ws + 27262976);   // 8 MB
  u16* hq   = (u16*)(ws + 35651584);   // 8 MB
  u16* hk   = (u16*)(ws + 44040192);   // 8 MB
  float* pos = (float*)(ws + 52428800); // 16 KB
  u16* Qb  = xb;
  u16* Kb  = pwb;
  u16* Vtb = hq;
  u16* A2  = hk;

  k_conv_cum<<<9218, 256, 0, stream>>>(x, pw, ow, lam, xb, pwb, owb, pos);
  k_gemm1<<<dim3(32, 32), 256, 0, stream>>>(xb, pwb, pb, hu, hv, hq, hk);
  k_rope_vt<<<3072, 256, 0, stream>>>(hq, hk, hv, pos, qg, kg, vg, hsc, Qb, Kb, Vtb);
  k_attn<<<1024, 256, 0, stream>>>(Qb, Kb, Vtb, tpb, hu, A2);
  k_gemm2<<<dim3(8, 32), 256, 0, stream>>>(A2, owb, ob, x, out);
  k_ln<<<4096, 256, 0, stream>>>(out, lng, lnb);
}

// Round 5
// 311.647 us; speedup vs baseline: 1.0614x; 1.0614x over previous
//
#include <hip/hip_runtime.h>
#include <cstdint>
#include <cstddef>

typedef unsigned short u16;
typedef __attribute__((ext_vector_type(8))) short short8v;   // 8 x bf16 (4 VGPRs)
typedef __attribute__((ext_vector_type(4))) float f32x4;

#define B_   2
#define L_   2048
#define D_   1024
#define NH_  16
#define DH_  64
#define M_   (B_*L_)      /* 4096 */
#define N4_  (4*D_)       /* 4096 */

__device__ __forceinline__ float bf2f(u16 u) {
  union { float f; unsigned int i; } v; v.i = ((unsigned int)u) << 16; return v.f;
}
__device__ __forceinline__ u16 f2bf(float f) {
  union { float f; unsigned int i; } v; v.f = f;
  unsigned int x = v.i;
  return (u16)((x + 0x7fffu + ((x >> 16) & 1u)) >> 16);   // RNE
}
__device__ __forceinline__ unsigned int pk_bf16(float a, float b) {
#if __has_builtin(__builtin_amdgcn_cvt_pk_bf16_f32)
  auto r = __builtin_amdgcn_cvt_pk_bf16_f32(a, b);
  union { decltype(r) v; unsigned int u; } c; c.v = r; return c.u;
#else
  return (unsigned int)f2bf(a) | ((unsigned int)f2bf(b) << 16);
#endif
}
__device__ __forceinline__ float siluf(float x) { return x / (1.0f + __expf(-x)); }

// async global->LDS, 16B per lane. LDS dest = wave-uniform base + lane*16.
__device__ __forceinline__ void gl2lds16(const u16* g, u16* l) {
  __builtin_amdgcn_global_load_lds(
      (const __attribute__((address_space(1))) unsigned int*)(const void*)g,
      (__attribute__((address_space(3))) unsigned int*)(void*)l,
      16, 0, 0);
}

// ---------------------------------------------------------------- convert + cumsum (fused)
__global__ __launch_bounds__(256) void k_conv_cum(const float* __restrict__ x,
                                                  const float* __restrict__ pw,
                                                  const float* __restrict__ ow,
                                                  const float* __restrict__ lam,
                                                  u16* __restrict__ xb,
                                                  u16* __restrict__ pwb,
                                                  u16* __restrict__ owb,
                                                  float* __restrict__ pos) {
  const int NX = M_ * D_ / 4, NP = N4_ * D_ / 4;
  int bid = blockIdx.x;
  int tid = threadIdx.x;
  if (bid < 9216) {
    int i = bid * 256 + tid;
    const float* src; u16* dst; int j;
    if (i < NX)            { src = x;  dst = xb;  j = i; }
    else if (i < NX + NP)  { src = pw; dst = pwb; j = i - NX; }
    else                   { src = ow; dst = owb; j = i - NX - NP; }
    float4 v = ((const float4*)src)[j];
    ushort4 o; o.x = f2bf(v.x); o.y = f2bf(v.y); o.z = f2bf(v.z); o.w = f2bf(v.w);
    ((ushort4*)dst)[j] = o;
  } else {
    int b = bid - 9216;
    const float* in = lam + (size_t)b * L_;
    float* out = pos + (size_t)b * L_;
    float loc[8], s = 0.0f;
#pragma unroll
    for (int i = 0; i < 8; ++i) { loc[i] = in[tid * 8 + i]; s += loc[i]; }
    __shared__ float sb[256];
    sb[tid] = s;
    __syncthreads();
    for (int off = 1; off < 256; off <<= 1) {
      float t = (tid >= off) ? sb[tid - off] : 0.0f;
      __syncthreads();
      sb[tid] += t;
      __syncthreads();
    }
    float run = sb[tid] - s;   // exclusive prefix
#pragma unroll
    for (int i = 0; i < 8; ++i) { run += loc[i]; out[tid * 8 + i] = run; }
  }
}

// ---------------------------------------------------------------- GEMM1: h = silu(x @ pw^T + pb), split u/v/q/k
// double-buffered single-barrier K-loop; swizzled LDS (conflict-free frag reads)
__global__ __launch_bounds__(256, 4) void k_gemm1(const u16* __restrict__ A,
                                                  const u16* __restrict__ Bw,
                                                  const float* __restrict__ bias,
                                                  u16* __restrict__ hu, u16* __restrict__ hv,
                                                  u16* __restrict__ hq, u16* __restrict__ hk) {
  const int K = D_;
  int bn = blockIdx.x, bm = blockIdx.y, tid = threadIdx.x;
  int w = tid >> 6, lane = tid & 63, quad = lane >> 4, r16 = lane & 15;
  __shared__ __align__(16) u16 As[8192], Bs[8192];   // 2 buffers x 128x32
  const u16* gA = A  + (size_t)(bm * 128) * K;
  const u16* gB = Bw + (size_t)(bn * 128) * K;
  int srow = tid >> 2, sc = tid & 3;
  // prologue stage(0)
#pragma unroll
  for (int s = 0; s < 2; ++s) {
    int row = s * 64 + srow;
    int q = (sc - (row >> 1)) & 3;
    gl2lds16(gA + (size_t)row * K + q * 8, As + s * 2048 + w * 512);
    gl2lds16(gB + (size_t)row * K + q * 8, Bs + s * 2048 + w * 512);
  }
  f32x4 acc[4][4] = {};
  int wm = w & 1, wn = w >> 1;
  const int rowb = wm * 64, colb = wn * 64;
  for (int n = 0; n < 32; ++n) {
    __syncthreads();                       // drains stage(n)
    if (n + 1 < 32) {
      int kt = (n + 1) * 32, pb = (n + 1) & 1;
#pragma unroll
      for (int s = 0; s < 2; ++s) {
        int row = s * 64 + srow;
        int q = (sc - (row >> 1)) & 3;
        gl2lds16(gA + (size_t)row * K + kt + q * 8, As + pb * 4096 + s * 2048 + w * 512);
        gl2lds16(gB + (size_t)row * K + kt + q * 8, Bs + pb * 4096 + s * 2048 + w * 512);
      }
    }
    const u16* Ab = As + (n & 1) * 4096;
    const u16* Bb = Bs + (n & 1) * 4096;
    short8v af[4], bf[4];
#pragma unroll
    for (int mi = 0; mi < 4; ++mi) {
      int row = rowb + mi * 16 + r16;
      af[mi] = *(const short8v*)(Ab + (row * 4 + ((quad + (row >> 1)) & 3)) * 8);
    }
#pragma unroll
    for (int ni = 0; ni < 4; ++ni) {
      int row = colb + ni * 16 + r16;
      bf[ni] = *(const short8v*)(Bb + (row * 4 + ((quad + (row >> 1)) & 3)) * 8);
    }
#pragma unroll
    for (int mi = 0; mi < 4; ++mi)
#pragma unroll
      for (int ni = 0; ni < 4; ++ni)
        acc[mi][ni] = __builtin_amdgcn_mfma_f32_16x16x32_bf16(af[mi], bf[ni], acc[mi][ni], 0, 0, 0);
  }
  int nb = (bn * 128) >> 10;                 // which of u/v/q/k
  u16* dst = (nb == 0) ? hu : (nb == 1) ? hv : (nb == 2) ? hq : hk;
  int cbase = (bn * 128) & 1023;
  int row0 = bm * 128 + rowb;
#pragma unroll
  for (int ni = 0; ni < 4; ++ni) {
    int gcol = bn * 128 + colb + ni * 16 + r16;
    int lcol = cbase + colb + ni * 16 + r16;
    float bb = bias[gcol];
#pragma unroll
    for (int mi = 0; mi < 4; ++mi)
#pragma unroll
      for (int r = 0; r < 4; ++r) {
        int row = row0 + mi * 16 + quad * 4 + r;
        dst[(size_t)row * D_ + lcol] = f2bf(siluf(acc[mi][ni][r] + bb));
      }
  }
}

// ---------------------------------------------------------------- RoPE + gates (+head_scale into Q) and V gate+transpose (fused)
__global__ __launch_bounds__(256) void k_rope_vt(const u16* __restrict__ hq, const u16* __restrict__ hk,
                                                 const u16* __restrict__ hv,
                                                 const float* __restrict__ pos,
                                                 const float* __restrict__ qg, const float* __restrict__ kg,
                                                 const float* __restrict__ vg,
                                                 const float* __restrict__ hsc,
                                                 u16* __restrict__ Qb, u16* __restrict__ Kb,
                                                 u16* __restrict__ Vtb) {
  int bid = blockIdx.x;
  int tid = threadIdx.x;
  if (bid < 2048) {
    int idx = bid * 256 + tid;   // (bh*2048 + l)*8 + j4
    int j4 = idx & 7;
    int l  = (idx >> 3) & 2047;
    int bh = idx >> 14;
    int b = bh >> 4, hh = bh & 15;
    int row = b * L_ + l;
    float p = pos[row];
    float qs = qg[(size_t)row * NH_ + hh] * hsc[hh];
    float kgv = kg[(size_t)row * NH_ + hh];
    const u16* hqr = hq + (size_t)row * D_ + hh * DH_ + j4 * 8;
    const u16* hkr = hk + (size_t)row * D_ + hh * DH_ + j4 * 8;
    short8v qv = *(const short8v*)hqr;
    short8v kv = *(const short8v*)hkr;
    size_t ob = ((size_t)bh * L_ + l) * DH_ + j4 * 4;
    u16 qeo[4], qoo[4], keo[4], koo[4];
#pragma unroll
    for (int t = 0; t < 4; ++t) {
      int j = j4 * 4 + t;
      float inv = __expf(-(float)j * 0.28782313662425574f);  // 10000^(-2j/64)
      float a = p * inv;
      float c, s;
      __sincosf(a, &s, &c);
      float qe = bf2f((u16)qv[2 * t]), qo = bf2f((u16)qv[2 * t + 1]);
      float ke = bf2f((u16)kv[2 * t]), ko = bf2f((u16)kv[2 * t + 1]);
      qeo[t] = f2bf((qe * c - qo * s) * qs);
      qoo[t] = f2bf((qe * s + qo * c) * qs);
      keo[t] = f2bf((ke * c - ko * s) * kgv);
      koo[t] = f2bf((ke * s + ko * c) * kgv);
    }
    *(ushort4*)(Qb + ob)      = make_ushort4(qeo[0], qeo[1], qeo[2], qeo[3]);
    *(ushort4*)(Qb + ob + 32) = make_ushort4(qoo[0], qoo[1], qoo[2], qoo[3]);
    *(ushort4*)(Kb + ob)      = make_ushort4(keo[0], keo[1], keo[2], keo[3]);
    *(ushort4*)(Kb + ob + 32) = make_ushort4(koo[0], koo[1], koo[2], koo[3]);
  } else {
    int b2 = bid - 2048;
    int lt = b2 & 31;           // l-tile
    int bh = b2 >> 5;
    int b = bh >> 4, hh = bh & 15;
    __shared__ u16 t[64][68];   // pad to break transpose conflicts
    {
      int r = tid >> 2, cg = tid & 3;
      int row = b * L_ + lt * 64 + r;
      float gv = vg[(size_t)row * NH_ + hh];
      const u16* src = hv + (size_t)row * D_ + hh * DH_ + cg * 16;
      short8v v0 = ((const short8v*)src)[0];
      short8v v1 = ((const short8v*)src)[1];
#pragma unroll
      for (int e = 0; e < 8; ++e) {
        t[r][cg * 16 + e]     = f2bf(bf2f((u16)v0[e]) * gv);
        t[r][cg * 16 + 8 + e] = f2bf(bf2f((u16)v1[e]) * gv);
      }
    }
    __syncthreads();
    {
      int d = tid >> 2, lg = tid & 3;
      short8v o0, o1;
#pragma unroll
      for (int e = 0; e < 8; ++e) o0[e] = (short)t[lg * 16 + e][d];
#pragma unroll
      for (int e = 0; e < 8; ++e) o1[e] = (short)t[lg * 16 + 8 + e][d];
      u16* dst = Vtb + ((size_t)bh * DH_ + d) * L_ + lt * 64 + lg * 16;
      ((short8v*)dst)[0] = o0;
      ((short8v*)dst)[1] = o1;
    }
  }
}

// ---------------------------------------------------------------- fused causal gated attention + u-multiply
// v5: v4 S^T structure + bias pipelined one iteration ahead (registers, reloaded after b2)
//     + Ps row-rotation rot(i)=((i>>3)&1)*8 on write+read
__global__ __launch_bounds__(256, 3) void k_attn(const u16* __restrict__ Qb, const u16* __restrict__ Kb,
                                                 const u16* __restrict__ Vtb, const float* __restrict__ tpb,
                                                 const u16* __restrict__ hu, u16* __restrict__ A2) {
  int id = blockIdx.x;
  int group = id >> 5, bh = id & 31;
  int i64 = (group & 1) ? (group >> 1) : (31 - (group >> 1));
  int jmax = i64 >> 1;
  int b = bh >> 4, hh = bh & 15;
  int tid = threadIdx.x, w = tid >> 6, lane = tid & 63, quad = lane >> 4, r16 = lane & 15;
  int wj = w & 1, wi = w >> 1;
  __shared__ __align__(16) u16 Ks[8192];   // 2 k-slices x (128 j x 32 d), content-swizzled
  __shared__ __align__(16) u16 Vs[8192];   // 4 l-slices x (64 d x 32 l), content-swizzled
  __shared__ __align__(16) u16 Ps[8704];   // 64 i x 128 j bf16 P, row stride 136, rotated
  const size_t bhbase = (size_t)bh * L_ * DH_;
  int gibase = i64 * 64 + wi * 32;
  // Q fragments (B-operand: n=i, k=d)
  const u16* qt = Qb + bhbase + (size_t)gibase * DH_;
  short8v bq[2][2];
#pragma unroll
  for (int ks = 0; ks < 2; ++ks)
#pragma unroll
    for (int ti = 0; ti < 2; ++ti)
      bq[ks][ti] = *(const short8v*)(qt + (size_t)(ti * 16 + r16) * DH_ + ks * 32 + quad * 8);
  // stage K(0)
#pragma unroll
  for (int s = 0; s < 4; ++s) {
    int row = (s & 1) * 64 + (tid >> 2);
    int q = ((tid & 3) - (row >> 1)) & 3;
    gl2lds16(Kb + bhbase + (size_t)row * DH_ + (s >> 1) * 32 + q * 8, Ks + s * 2048 + w * 512);
  }
  // bias rows (per lane, per ti)
  const float* bpr[2];
#pragma unroll
  for (int ti = 0; ti < 2; ++ti)
    bpr[ti] = tpb + ((size_t)b * L_ + gibase + ti * 16 + r16) * L_ + wj * 64 + quad * 4;
  // prefetch bias(0)
  float4 bv[4][2];
#pragma unroll
  for (int tj = 0; tj < 4; ++tj)
#pragma unroll
    for (int ti = 0; ti < 2; ++ti)
      if (tj * 16 + wj * 64 <= gibase + ti * 16 + 15)
        bv[tj][ti] = *(const float4*)(bpr[ti] + tj * 16);
  f32x4 accy[4] = {};
  int gimax_w = i64 * 64 + w * 16 + 15;
  for (int jt = 0; jt <= jmax; ++jt) {
    __syncthreads();   // b1: K(jt)+bias(jt) drained (covered by prior PV); Vs/Ps free
    // stage V(jt)
#pragma unroll
    for (int s = 0; s < 4; ++s) {
      int row = tid >> 2;
      int q = ((tid & 3) - (row >> 1)) & 3;
      gl2lds16(Vtb + bhbase + (size_t)row * L_ + jt * 128 + s * 32 + q * 8, Vs + s * 2048 + w * 512);
    }
    // ---- S^T = K·Q^T; bias (already in regs) + silu + mask + pack in epilogue
#pragma unroll
    for (int tj = 0; tj < 4; ++tj) {
      int jlo = jt * 128 + wj * 64 + tj * 16;     // global j base of tile
      bool anyM = jlo <= gibase + 31;
      short8v ak0, ak1;
      if (anyM) {
        int row = wj * 64 + tj * 16 + r16;
        int sw = (quad + (row >> 1)) & 3;
        ak0 = *(const short8v*)(Ks + (row * 4 + sw) * 8);
        ak1 = *(const short8v*)(Ks + 4096 + (row * 4 + sw) * 8);
      }
#pragma unroll
      for (int ti = 0; ti < 2; ++ti) {
        int gmaxt = gibase + ti * 16 + 15;
        bool doM = jlo <= gmaxt;              // tile has any unmasked element
        bool doW = (jlo & ~31) <= gmaxt;      // tile's k-slice is read by PV
        if (!doW) continue;
        unsigned int p01 = 0, p23 = 0;
        if (doM) {
          int gi = gibase + ti * 16 + r16;
          f32x4 acc = {};
          acc = __builtin_amdgcn_mfma_f32_16x16x32_bf16(ak0, bq[0][ti], acc, 0, 0, 0);
          acc = __builtin_amdgcn_mfma_f32_16x16x32_bf16(ak1, bq[1][ti], acc, 0, 0, 0);
          int j0 = jlo + quad * 4;
          float4 bvv = bv[tj][ti];
          float v0 = (j0     <= gi) ? siluf(fmaf(4.0f, bvv.x, acc[0])) : 0.0f;
          float v1 = (j0 + 1 <= gi) ? siluf(fmaf(4.0f, bvv.y, acc[1])) : 0.0f;
          float v2 = (j0 + 2 <= gi) ? siluf(fmaf(4.0f, bvv.z, acc[2])) : 0.0f;
          float v3 = (j0 + 3 <= gi) ? siluf(fmaf(4.0f, bvv.w, acc[3])) : 0.0f;
          p01 = pk_bf16(v0, v1);
          p23 = pk_bf16(v2, v3);
        }
        int iloc = wi * 32 + ti * 16 + r16;
        int rot = ((iloc >> 3) & 1) << 3;
        int col = wj * 64 + tj * 16 + quad * 4;
        *(uint2*)(Ps + iloc * 136 + (col & 96) + (((col & 31) + rot) & 31)) = make_uint2(p01, p23);
      }
    }
    __syncthreads();   // b2: Ps ready; V(jt) drained (covered by QK)
    // stage K(jt+1) and prefetch bias(jt+1) (drain at next b1, covered by PV)
    if (jt < jmax) {
      const size_t kb = bhbase + (size_t)(jt + 1) * 128 * DH_;
#pragma unroll
      for (int s = 0; s < 4; ++s) {
        int row = (s & 1) * 64 + (tid >> 2);
        int q = ((tid & 3) - (row >> 1)) & 3;
        gl2lds16(Kb + kb + (size_t)row * DH_ + (s >> 1) * 32 + q * 8, Ks + s * 2048 + w * 512);
      }
      int jn = (jt + 1) * 128;
#pragma unroll
      for (int tj = 0; tj < 4; ++tj)
#pragma unroll
        for (int ti = 0; ti < 2; ++ti)
          if (jn + tj * 16 + wj * 64 <= gibase + ti * 16 + 15)
            bv[tj][ti] = *(const float4*)(bpr[ti] + jn + tj * 16);
    }
    // ---- PV: pure reads + mfma (wave w: rows w*16..w*16+15)
#pragma unroll
    for (int ks = 0; ks < 4; ++ks) {
      if (jt * 128 + ks * 32 > gimax_w) continue;
      int li = w * 16 + r16;
      int rotr = ((li >> 3) & 1) << 3;
      short8v pa = *(const short8v*)(Ps + li * 136 + ks * 32 + ((quad * 8 + rotr) & 31));
#pragma unroll
      for (int ni = 0; ni < 4; ++ni) {
        int row = ni * 16 + r16;
        short8v vb = *(const short8v*)(Vs + ks * 2048 + (row * 4 + ((quad + (row >> 1)) & 3)) * 8);
        accy[ni] = __builtin_amdgcn_mfma_f32_16x16x32_bf16(pa, vb, accy[ni], 0, 0, 0);
      }
    }
  }
  // final epilogue: y * u -> A2 (b, l, h*64+d) bf16
#pragma unroll
  for (int ni = 0; ni < 4; ++ni) {
    int d = ni * 16 + r16;
#pragma unroll
    for (int r = 0; r < 4; ++r) {
      int lr = w * 16 + quad * 4 + r;
      size_t rowg = (size_t)b * L_ + (size_t)i64 * 64 + lr;
      float u = bf2f(hu[rowg * D_ + hh * DH_ + d]);
      A2[rowg * D_ + hh * DH_ + d] = f2bf(accy[ni][r] * u);
    }
  }
}

// ---------------------------------------------------------------- GEMM2: r = (y*u) @ ow^T + ob + x
__global__ __launch_bounds__(256, 4) void k_gemm2(const u16* __restrict__ A,
                                                  const u16* __restrict__ Bw,
                                                  const float* __restrict__ bias,
                                                  const float* __restrict__ xres,
                                                  float* __restrict__ out) {
  const int K = D_;
  int bn = blockIdx.x, bm = blockIdx.y, tid = threadIdx.x;
  int w = tid >> 6, lane = tid & 63, quad = lane >> 4, r16 = lane & 15;
  __shared__ __align__(16) u16 As[8192], Bs[8192];
  const u16* gA = A  + (size_t)(bm * 128) * K;
  const u16* gB = Bw + (size_t)(bn * 128) * K;
  int srow = tid >> 2, sc = tid & 3;
#pragma unroll
  for (int s = 0; s < 2; ++s) {
    int row = s * 64 + srow;
    int q = (sc - (row >> 1)) & 3;
    gl2lds16(gA + (size_t)row * K + q * 8, As + s * 2048 + w * 512);
    gl2lds16(gB + (size_t)row * K + q * 8, Bs + s * 2048 + w * 512);
  }
  f32x4 acc[4][4] = {};
  int wm = w & 1, wn = w >> 1;
  const int rowb = wm * 64, colb = wn * 64;
  for (int n = 0; n < 32; ++n) {
    __syncthreads();
    if (n + 1 < 32) {
      int kt = (n + 1) * 32, pb = (n + 1) & 1;
#pragma unroll
      for (int s = 0; s < 2; ++s) {
        int row = s * 64 + srow;
        int q = (sc - (row >> 1)) & 3;
        gl2lds16(gA + (size_t)row * K + kt + q * 8, As + pb * 4096 + s * 2048 + w * 512);
        gl2lds16(gB + (size_t)row * K + kt + q * 8, Bs + pb * 4096 + s * 2048 + w * 512);
      }
    }
    const u16* Ab = As + (n & 1) * 4096;
    const u16* Bb = Bs + (n & 1) * 4096;
    short8v af[4], bf[4];
#pragma unroll
    for (int mi = 0; mi < 4; ++mi) {
      int row = rowb + mi * 16 + r16;
      af[mi] = *(const short8v*)(Ab + (row * 4 + ((quad + (row >> 1)) & 3)) * 8);
    }
#pragma unroll
    for (int ni = 0; ni < 4; ++ni) {
      int row = colb + ni * 16 + r16;
      bf[ni] = *(const short8v*)(Bb + (row * 4 + ((quad + (row >> 1)) & 3)) * 8);
    }
#pragma unroll
    for (int mi = 0; mi < 4; ++mi)
#pragma unroll
      for (int ni = 0; ni < 4; ++ni)
        acc[mi][ni] = __builtin_amdgcn_mfma_f32_16x16x32_bf16(af[mi], bf[ni], acc[mi][ni], 0, 0, 0);
  }
  int row0 = bm * 128 + rowb, col0 = bn * 128 + colb;
#pragma unroll
  for (int ni = 0; ni < 4; ++ni) {
    int col = col0 + ni * 16 + r16;
    float bb = bias[col];
#pragma unroll
    for (int mi = 0; mi < 4; ++mi)
#pragma unroll
      for (int r = 0; r < 4; ++r) {
        int row = row0 + mi * 16 + quad * 4 + r;
        out[(size_t)row * D_ + col] = acc[mi][ni][r] + bb + xres[(size_t)row * D_ + col];
      }
  }
}

// ---------------------------------------------------------------- LayerNorm (in place on d_out)
__global__ __launch_bounds__(256) void k_ln(float* __restrict__ r,
                                            const float* __restrict__ g,
                                            const float* __restrict__ be) {
  int row = blockIdx.x, tid = threadIdx.x;
  float* pr = r + (size_t)row * D_;
  __shared__ float s1[4], s2[4];
  float v[4];
#pragma unroll
  for (int i = 0; i < 4; ++i) v[i] = pr[i * 256 + tid];
  float s = v[0] + v[1] + v[2] + v[3];
#pragma unroll
  for (int o = 32; o > 0; o >>= 1) s += __shfl_down(s, o, 64);
  if ((tid & 63) == 0) s1[tid >> 6] = s;
  __syncthreads();
  float mu = (s1[0] + s1[1] + s1[2] + s1[3]) * (1.0f / D_);
  float d = 0.0f;
#pragma unroll
  for (int i = 0; i < 4; ++i) { float t = v[i] - mu; d += t * t; }
#pragma unroll
  for (int o = 32; o > 0; o >>= 1) d += __shfl_down(d, o, 64);
  if ((tid & 63) == 0) s2[tid >> 6] = d;
  __syncthreads();
  float var = (s2[0] + s2[1] + s2[2] + s2[3]) * (1.0f / D_);
  float inv = rsqrtf(var + 1e-5f);
#pragma unroll
  for (int i = 0; i < 4; ++i) {
    int c = i * 256 + tid;
    pr[c] = (v[i] - mu) * inv * g[c] + be[c];
  }
}

// ---------------------------------------------------------------- launch
extern "C" void kernel_launch(void* const* d_in, const int* in_sizes, int n_in,
                              void* d_out, int out_size, void* d_ws, size_t ws_size,
                              hipStream_t stream) {
  const float* x   = (const float*)d_in[0];
  // d_in[1] attn_mask: deterministic causal tril -> not read
  // d_in[2] ts: unused by reference
  const float* lam = (const float*)d_in[3];
  const float* qg  = (const float*)d_in[4];
  const float* kg  = (const float*)d_in[5];
  const float* vg  = (const float*)d_in[6];
  const float* tpb = (const float*)d_in[7];
  const float* pw  = (const float*)d_in[8];
  const float* pb  = (const float*)d_in[9];
  const float* ow  = (const float*)d_in[10];
  const float* ob  = (const float*)d_in[11];
  const float* hsc = (const float*)d_in[12];
  const float* lng = (const float*)d_in[13];
  const float* lnb = (const float*)d_in[14];
  float* out = (float*)d_out;

  char* ws = (char*)d_ws;
  // layout (bytes). aliasing: Qb<-xb, Kb<-pwb, Vtb<-hq, A2<-hk (all after last read)
  u16* xb   = (u16*)(ws + 0);          // 8 MB   x bf16
  u16* pwb  = (u16*)(ws + 8388608);    // 8 MB   proj_w bf16
  u16* owb  = (u16*)(ws + 16777216);   // 2 MB   out_w bf16
  u16* hu   = (u16*)(ws + 18874368);   // 8 MB
  u16* hv   = (u16*)(ws + 27262976);   // 8 MB
  u16* hq   = (u16*)(ws + 35651584);   // 8 MB
  u16* hk   = (u16*)(ws + 44040192);   // 8 MB
  float* pos = (float*)(ws + 52428800); // 16 KB
  u16* Qb  = xb;
  u16* Kb  = pwb;
  u16* Vtb = hq;
  u16* A2  = hk;

  k_conv_cum<<<9218, 256, 0, stream>>>(x, pw, ow, lam, xb, pwb, owb, pos);
  k_gemm1<<<dim3(32, 32), 256, 0, stream>>>(xb, pwb, pb, hu, hv, hq, hk);
  k_rope_vt<<<3072, 256, 0, stream>>>(hq, hk, hv, pos, qg, kg, vg, hsc, Qb, Kb, Vtb);
  k_attn<<<1024, 256, 0, stream>>>(Qb, Kb, Vtb, tpb, hu, A2);
  k_gemm2<<<dim3(8, 32), 256, 0, stream>>>(A2, owb, ob, x, out);
  k_ln<<<4096, 256, 0, stream>>>(out, lng, lnb);
}